// Round 2
// baseline (475.721 us; speedup 1.0000x reference)
//
#include <hip/hip_runtime.h>
#include <hip/hip_bf16.h>

// Problem constants (fixed by the reference module)
static constexpr int B_  = 2;
static constexpr int N_  = 4096;
static constexpr int D_  = 512;
static constexpr int H_  = 8;
static constexpr int P_  = 9;
static constexpr int HD_ = 64;   // head dim
static constexpr int GH_ = 16;   // grid h
static constexpr int GW_ = 256;  // grid w
static constexpr int M_  = B_ * N_;  // 8192 tokens

// Y[m][n] = sum_k A[m][k] * W[n][k] + bias[n]   (i.e. A @ W^T + b), all fp32.
// A: (M,K) row-major, W: (Nout,K) row-major.
// 64x64 tile per 256-thread block, BK=16, fp32 accumulate.
template <bool TANH>
__global__ __launch_bounds__(256) void gemm_bt(const float* __restrict__ A,
                                               const float* __restrict__ W,
                                               const float* __restrict__ bias,
                                               float* __restrict__ Y,
                                               int M, int K, int Nout) {
    __shared__ float As[16][64];  // [k][m]: inner-loop reads are ds_read_b128, conflict-free
    __shared__ float Bs[16][64];  // [k][n]

    const int t  = threadIdx.x;
    const int m0 = blockIdx.y * 64;
    const int n0 = blockIdx.x * 64;
    const int row_ld = t >> 2;        // 0..63
    const int kk_ld  = (t & 3) * 4;   // 0,4,8,12
    const int ty = t >> 4;            // 0..15
    const int tx = t & 15;            // 0..15

    float acc[4][4] = {};

    for (int k0 = 0; k0 < K; k0 += 16) {
        // stage A tile: one float4 (16B) per thread
        {
            float4 u = *reinterpret_cast<const float4*>(
                A + (size_t)(m0 + row_ld) * K + k0 + kk_ld);
            As[kk_ld + 0][row_ld] = u.x;
            As[kk_ld + 1][row_ld] = u.y;
            As[kk_ld + 2][row_ld] = u.z;
            As[kk_ld + 3][row_ld] = u.w;
        }
        // stage W tile (bounds-checked: Nout=144 is not a multiple of 64)
        {
            const int wr = n0 + row_ld;
            float4 u = make_float4(0.f, 0.f, 0.f, 0.f);
            if (wr < Nout)
                u = *reinterpret_cast<const float4*>(
                    W + (size_t)wr * K + k0 + kk_ld);
            Bs[kk_ld + 0][row_ld] = u.x;
            Bs[kk_ld + 1][row_ld] = u.y;
            Bs[kk_ld + 2][row_ld] = u.z;
            Bs[kk_ld + 3][row_ld] = u.w;
        }
        __syncthreads();

#pragma unroll
        for (int kk = 0; kk < 16; ++kk) {
            float4 av = *reinterpret_cast<const float4*>(&As[kk][ty * 4]);
            float4 bv = *reinterpret_cast<const float4*>(&Bs[kk][tx * 4]);
            float a[4] = {av.x, av.y, av.z, av.w};
            float b[4] = {bv.x, bv.y, bv.z, bv.w};
#pragma unroll
            for (int i = 0; i < 4; ++i)
#pragma unroll
                for (int j = 0; j < 4; ++j) acc[i][j] = fmaf(a[i], b[j], acc[i][j]);
        }
        __syncthreads();
    }

#pragma unroll
    for (int i = 0; i < 4; ++i) {
        const int m = m0 + ty * 4 + i;
#pragma unroll
        for (int j = 0; j < 4; ++j) {
            const int nn = n0 + tx * 4 + j;
            if (nn < Nout) {
                float v = acc[i][j] + bias[nn];
                if (TANH) v = tanhf(v) * 4.0f;  // OFFSET_SCALE
                Y[(size_t)m * Nout + nn] = v;
            }
        }
    }
}

// One wave per (b, head, token). lane = channel d in [0,64).
// q_ws:  (B*N, 512) fp32      [token][h*64+d]
// off_ws:(B*N, 144) fp32      [token][h*18+p*2+c]   (already tanh*4)
// kv_ws: (B*N, 1024) fp32     [token][c], k at c=h*64+d, v at c=512+h*64+d
// aout:  (B*N, 512) fp32 merged-head attention output
__global__ __launch_bounds__(256) void attn_sample(const float* __restrict__ q_ws,
                                                   const float* __restrict__ off_ws,
                                                   const float* __restrict__ kv_ws,
                                                   float* __restrict__ aout) {
    const int lane = threadIdx.x & 63;
    const int wg   = blockIdx.x * 4 + (threadIdx.x >> 6);  // global wave id
    const int b    = wg >> 15;         // / (H*N) = 32768
    const int hh   = (wg >> 12) & 7;   // / N, % H
    const int n    = wg & 4095;        // % N

    const int px = n & (GW_ - 1);
    const int py = n >> 8;  // n / GW_

    const size_t tok0 = (size_t)b * N_;
    const float qv = q_ws[(tok0 + n) * 512 + hh * 64 + lane];
    const float* offp = off_ws + (tok0 + n) * 144 + hh * 18;
    const float* kvb  = kv_ws + tok0 * 1024 + hh * 64;  // + tok*1024 (+512 for v)

    float lg[9], sv[9];
    float mx = -1e30f;

#pragma unroll
    for (int p = 0; p < P_; ++p) {
        const float dx = offp[p * 2 + 0];
        const float dy = offp[p * 2 + 1];
        const float sx = (float)px + dx;
        const float sy = (float)py + dy;
        const float x0f = floorf(sx), y0f = floorf(sy);
        const int x0 = (int)x0f, y0 = (int)y0f;
        const float wx1 = sx - x0f, wy1 = sy - y0f;
        const float wx0 = 1.0f - wx1, wy0 = 1.0f - wy1;

        float kacc = 0.0f, vacc = 0.0f;
#pragma unroll
        for (int c = 0; c < 4; ++c) {
            const int xi = x0 + (c & 1);
            const int yi = y0 + (c >> 1);
            const float wgt = ((c & 1) ? wx1 : wx0) * ((c >> 1) ? wy1 : wy0);
            // corner coords are wave-uniform -> uniform branch, coalesced 256B row loads
            if (xi >= 0 && xi < GW_ && yi >= 0 && yi < GH_) {
                const float* row = kvb + (size_t)(yi * GW_ + xi) * 1024;
                kacc = fmaf(wgt, row[lane], kacc);
                vacc = fmaf(wgt, row[512 + lane], vacc);
            }
        }
        // logit: full-wave dot(q, sampled_k)
        float tsum = qv * kacc;
#pragma unroll
        for (int s = 32; s > 0; s >>= 1) tsum += __shfl_xor(tsum, s, 64);
        lg[p] = tsum * 0.125f;  // HD^-0.5
        sv[p] = vacc;
        mx = fmaxf(mx, lg[p]);
    }

    float ssum = 0.0f, o = 0.0f;
#pragma unroll
    for (int p = 0; p < P_; ++p) {
        const float e = __expf(lg[p] - mx);
        ssum += e;
        o = fmaf(e, sv[p], o);
    }
    o /= ssum;

    aout[(tok0 + n) * 512 + hh * 64 + lane] = o;
}

extern "C" void kernel_launch(void* const* d_in, const int* in_sizes, int n_in,
                              void* d_out, int out_size, void* d_ws, size_t ws_size,
                              hipStream_t stream) {
    // Reference setup_inputs() builds float32 arrays -> cast per harness contract.
    const float* x    = (const float*)d_in[0];
    const float* Wq   = (const float*)d_in[1];
    const float* bq   = (const float*)d_in[2];
    const float* Woff = (const float*)d_in[3];
    const float* boff = (const float*)d_in[4];
    const float* Wkv  = (const float*)d_in[5];
    const float* bkv  = (const float*)d_in[6];
    const float* Wo   = (const float*)d_in[7];
    const float* bo   = (const float*)d_in[8];
    float* out = (float*)d_out;

    // Workspace layout (all fp32):
    float* q_ws   = (float*)d_ws;                           // 8192*512  = 16 MB
    float* off_ws = q_ws + (size_t)M_ * D_;                 // 8192*144  = 4.5 MB
    float* kv_ws  = off_ws + (size_t)M_ * (H_ * P_ * 2);    // 8192*1024 = 32 MB
    float* a_ws   = kv_ws + (size_t)M_ * (2 * D_);          // 8192*512  = 16 MB

    const dim3 blk(256);

    // q = x @ Wq^T + bq            (M x 512)
    gemm_bt<false><<<dim3(512 / 64, M_ / 64), blk, 0, stream>>>(
        x, Wq, bq, q_ws, M_, D_, 512);
    // off = tanh(x @ Woff^T + boff) * 4   (M x 144)
    gemm_bt<true><<<dim3((144 + 63) / 64, M_ / 64), blk, 0, stream>>>(
        x, Woff, boff, off_ws, M_, D_, 144);
    // kv = x @ Wkv^T + bkv         (M x 1024)
    gemm_bt<false><<<dim3(1024 / 64, M_ / 64), blk, 0, stream>>>(
        x, Wkv, bkv, kv_ws, M_, D_, 1024);

    // sampling + attention: one wave per (b, head, token)
    attn_sample<<<dim3((B_ * H_ * N_) / 4), blk, 0, stream>>>(q_ws, off_ws, kv_ws, a_ws);

    // out = attn_out @ Wo^T + bo   (M x 512), fp32 store
    gemm_bt<false><<<dim3(512 / 64, M_ / 64), blk, 0, stream>>>(
        a_ws, Wo, bo, out, M_, D_, 512);
}

// Round 3
// 292.660 us; speedup vs baseline: 1.6255x; 1.6255x over previous
//
#include <hip/hip_runtime.h>
#include <hip/hip_bf16.h>

// Problem constants (fixed by the reference module)
static constexpr int B_  = 2;
static constexpr int N_  = 4096;
static constexpr int D_  = 512;
static constexpr int H_  = 8;
static constexpr int P_  = 9;
static constexpr int GH_ = 16;   // grid h
static constexpr int GW_ = 256;  // grid w
static constexpr int M_  = B_ * N_;  // 8192 tokens

typedef __attribute__((ext_vector_type(8))) short bf16x8;
typedef __attribute__((ext_vector_type(4))) float f32x4;

__device__ __forceinline__ unsigned short f2b(float f) {
    __hip_bfloat16 h = __float2bfloat16(f);  // round-to-nearest
    return *reinterpret_cast<unsigned short*>(&h);
}
__device__ __forceinline__ float b2f(unsigned short u) {
    return __uint_as_float(((unsigned int)u) << 16);
}

// ---------------------------------------------------------------------------
// Cast fp32 -> bf16 for x, Wq, Wkv, Wo (4 elements / thread via float4)
// group ranges: x 1048576 | Wq 65536 | Wkv 131072 | Wo 65536  (in float4 units)
__global__ __launch_bounds__(256) void cast_multi(const float* __restrict__ x,
                                                  const float* __restrict__ wq,
                                                  const float* __restrict__ wkv,
                                                  const float* __restrict__ wo,
                                                  unsigned short* __restrict__ xb,
                                                  unsigned short* __restrict__ wqb,
                                                  unsigned short* __restrict__ wkvb,
                                                  unsigned short* __restrict__ wob) {
    int g = blockIdx.x * 256 + threadIdx.x;
    const float* src; unsigned short* dst; int off;
    if (g < 1048576)               { src = x;   dst = xb;   off = g; }
    else if (g < 1048576 + 65536)  { src = wq;  dst = wqb;  off = g - 1048576; }
    else if (g < 1048576 + 196608) { src = wkv; dst = wkvb; off = g - 1048576 - 65536; }
    else                           { src = wo;  dst = wob;  off = g - 1048576 - 196608; }
    float4 v = reinterpret_cast<const float4*>(src)[off];
    ushort4 o;
    o.x = f2b(v.x); o.y = f2b(v.y); o.z = f2b(v.z); o.w = f2b(v.w);
    reinterpret_cast<ushort4*>(dst)[off] = o;
}

// ---------------------------------------------------------------------------
// fp32 vector GEMM (kept only for the offset head: precision-critical path)
// Y[m][n] = sum_k A[m][k]*W[n][k] + bias[n]; TANH applies tanh(v)*4.
template <bool TANH>
__global__ __launch_bounds__(256) void gemm_bt(const float* __restrict__ A,
                                               const float* __restrict__ W,
                                               const float* __restrict__ bias,
                                               float* __restrict__ Y,
                                               int M, int K, int Nout) {
    __shared__ float As[16][64];  // [k][m]
    __shared__ float Bs[16][64];  // [k][n]

    const int t  = threadIdx.x;
    const int m0 = blockIdx.y * 64;
    const int n0 = blockIdx.x * 64;
    const int row_ld = t >> 2;
    const int kk_ld  = (t & 3) * 4;
    const int ty = t >> 4;
    const int tx = t & 15;

    float acc[4][4] = {};

    for (int k0 = 0; k0 < K; k0 += 16) {
        {
            float4 u = *reinterpret_cast<const float4*>(
                A + (size_t)(m0 + row_ld) * K + k0 + kk_ld);
            As[kk_ld + 0][row_ld] = u.x;
            As[kk_ld + 1][row_ld] = u.y;
            As[kk_ld + 2][row_ld] = u.z;
            As[kk_ld + 3][row_ld] = u.w;
        }
        {
            const int wr = n0 + row_ld;
            float4 u = make_float4(0.f, 0.f, 0.f, 0.f);
            if (wr < Nout)
                u = *reinterpret_cast<const float4*>(
                    W + (size_t)wr * K + k0 + kk_ld);
            Bs[kk_ld + 0][row_ld] = u.x;
            Bs[kk_ld + 1][row_ld] = u.y;
            Bs[kk_ld + 2][row_ld] = u.z;
            Bs[kk_ld + 3][row_ld] = u.w;
        }
        __syncthreads();

#pragma unroll
        for (int kk = 0; kk < 16; ++kk) {
            float4 av = *reinterpret_cast<const float4*>(&As[kk][ty * 4]);
            float4 bv = *reinterpret_cast<const float4*>(&Bs[kk][tx * 4]);
            float a[4] = {av.x, av.y, av.z, av.w};
            float b[4] = {bv.x, bv.y, bv.z, bv.w};
#pragma unroll
            for (int i = 0; i < 4; ++i)
#pragma unroll
                for (int j = 0; j < 4; ++j) acc[i][j] = fmaf(a[i], b[j], acc[i][j]);
        }
        __syncthreads();
    }

#pragma unroll
    for (int i = 0; i < 4; ++i) {
        const int m = m0 + ty * 4 + i;
#pragma unroll
        for (int j = 0; j < 4; ++j) {
            const int nn = n0 + tx * 4 + j;
            if (nn < Nout) {
                float v = acc[i][j] + bias[nn];
                if (TANH) v = tanhf(v) * 4.0f;  // OFFSET_SCALE
                Y[(size_t)m * Nout + nn] = v;
            }
        }
    }
}

// ---------------------------------------------------------------------------
// bf16 MFMA GEMM: Y = A @ W^T + bias.  A:(M,K) bf16, W:(Nout,K) bf16.
// 128x128 tile / block (4 waves, each 64x64 via 4x4 of 16x16x32 MFMA), BK=32.
// Staging via global_load_lds width=16 (LDS layout = row-major [128][32],
// exactly the lane deposit order: wave-uniform base + lane*16B).
// OutMode: 0 = fp32 store, 1 = bf16 store, 2 = kv-interleave fp32 store.
template <int MODE>
__global__ __launch_bounds__(256) void gemm_mfma(const unsigned short* __restrict__ A,
                                                 const unsigned short* __restrict__ W,
                                                 const float* __restrict__ bias,
                                                 void* __restrict__ Yv,
                                                 int M, int K, int Nout) {
    __shared__ short As[128 * 32];
    __shared__ short Bs[128 * 32];

    const int t    = threadIdx.x;
    const int wave = t >> 6;
    const int lane = t & 63;
    const int wm   = wave & 1;   // wave quadrant in M
    const int wn   = wave >> 1;  // wave quadrant in N
    const int m0   = blockIdx.y * 128;
    const int n0   = blockIdx.x * 128;

    // staging indices: call c covers linear slots gi = wave*128 + c*64 + lane,
    // slot gi -> tile row gi>>2, col (gi&3)*8 (8 bf16 = 16 B per lane)
    const int gi0 = wave * 128 + lane;
    const int gi1 = gi0 + 64;
    const int rA0 = gi0 >> 2, c0 = (gi0 & 3) * 8;
    const int rA1 = gi1 >> 2, c1 = (gi1 & 3) * 8;

    const unsigned short* pa0 = A + (size_t)(m0 + rA0) * K + c0;
    const unsigned short* pa1 = A + (size_t)(m0 + rA1) * K + c1;
    const unsigned short* pw0 = W + (size_t)(n0 + rA0) * K + c0;
    const unsigned short* pw1 = W + (size_t)(n0 + rA1) * K + c1;

    short* ldsA0 = &As[wave * 1024];        // short units; 1024B per call-slot
    short* ldsA1 = &As[wave * 1024 + 512];
    short* ldsB0 = &Bs[wave * 1024];
    short* ldsB1 = &Bs[wave * 1024 + 512];

    f32x4 acc[4][4] = {};

    const int fr = lane & 15;          // fragment row (m for A, n for B)
    const int fk = (lane >> 4) * 8;    // fragment k offset

    for (int k0 = 0; k0 < K; k0 += 32) {
        __builtin_amdgcn_global_load_lds(
            (const __attribute__((address_space(1))) void*)(pa0 + k0),
            (__attribute__((address_space(3))) void*)ldsA0, 16, 0, 0);
        __builtin_amdgcn_global_load_lds(
            (const __attribute__((address_space(1))) void*)(pa1 + k0),
            (__attribute__((address_space(3))) void*)ldsA1, 16, 0, 0);
        __builtin_amdgcn_global_load_lds(
            (const __attribute__((address_space(1))) void*)(pw0 + k0),
            (__attribute__((address_space(3))) void*)ldsB0, 16, 0, 0);
        __builtin_amdgcn_global_load_lds(
            (const __attribute__((address_space(1))) void*)(pw1 + k0),
            (__attribute__((address_space(3))) void*)ldsB1, 16, 0, 0);
        __syncthreads();

        bf16x8 af[4], bf[4];
#pragma unroll
        for (int i = 0; i < 4; ++i)
            af[i] = *reinterpret_cast<const bf16x8*>(
                &As[(wm * 64 + i * 16 + fr) * 32 + fk]);
#pragma unroll
        for (int j = 0; j < 4; ++j)
            bf[j] = *reinterpret_cast<const bf16x8*>(
                &Bs[(wn * 64 + j * 16 + fr) * 32 + fk]);
#pragma unroll
        for (int i = 0; i < 4; ++i)
#pragma unroll
            for (int j = 0; j < 4; ++j)
                acc[i][j] = __builtin_amdgcn_mfma_f32_16x16x32_bf16(
                    af[i], bf[j], acc[i][j], 0, 0, 0);
        __syncthreads();
    }

    // epilogue: C/D layout col=lane&15 (n), row=(lane>>4)*4+reg (m)
    const int ecol = lane & 15;
    const int erow = (lane >> 4) * 4;
#pragma unroll
    for (int i = 0; i < 4; ++i) {
#pragma unroll
        for (int j = 0; j < 4; ++j) {
#pragma unroll
            for (int r = 0; r < 4; ++r) {
                const int m = m0 + wm * 64 + i * 16 + erow + r;
                const int n = n0 + wn * 64 + j * 16 + ecol;
                float v = acc[i][j][r] + bias[n];
                if (MODE == 0) {
                    ((float*)Yv)[(size_t)m * Nout + n] = v;
                } else if (MODE == 1) {
                    ((unsigned short*)Yv)[(size_t)m * Nout + n] = f2b(v);
                } else {  // kv interleave: [token][2*(h*64+d) + {0:k,1:v}]
                    float* Y = (float*)Yv;
                    if (n < 512) Y[(size_t)m * 1024 + 2 * n] = v;
                    else         Y[(size_t)m * 1024 + 2 * (n - 512) + 1] = v;
                }
            }
        }
    }
}

// ---------------------------------------------------------------------------
// One wave per (b, head, token). lane = channel d in [0,64).
// q_bf:  (B*N, 512) bf16
// off_ws:(B*N, 144) fp32   [token][h*18+p*2+c] (already tanh*4)
// kv2:   (B*N, 1024) fp32  [token][2*(h*64+d)+{0:k,1:v}]  -> float2 per (h,d)
// a_bf:  (B*N, 512) bf16 merged-head attention output
__global__ __launch_bounds__(256) void attn_sample(const unsigned short* __restrict__ q_bf,
                                                   const float* __restrict__ off_ws,
                                                   const float* __restrict__ kv2,
                                                   unsigned short* __restrict__ a_bf) {
    const int lane = threadIdx.x & 63;
    const int wg   = blockIdx.x * 4 + (threadIdx.x >> 6);
    const int b    = wg >> 15;
    const int hh   = (wg >> 12) & 7;
    const int n    = wg & 4095;

    const int px = n & (GW_ - 1);
    const int py = n >> 8;

    const size_t tok0 = (size_t)b * N_;
    const float qv = b2f(q_bf[(tok0 + n) * 512 + hh * 64 + lane]);
    const float* offp = off_ws + (tok0 + n) * 144 + hh * 18;
    const float* kvb  = kv2 + tok0 * 1024 + hh * 128;  // + row*1024, float2 at [lane]

    float lg[9], sv[9];
    float mx = -1e30f;

#pragma unroll
    for (int p = 0; p < P_; ++p) {
        const float dx = offp[p * 2 + 0];
        const float dy = offp[p * 2 + 1];
        const float sx = (float)px + dx;
        const float sy = (float)py + dy;
        const float x0f = floorf(sx), y0f = floorf(sy);
        const int x0 = (int)x0f, y0 = (int)y0f;
        const float wx1 = sx - x0f, wy1 = sy - y0f;
        const float wx0 = 1.0f - wx1, wy0 = 1.0f - wy1;

        float kacc = 0.0f, vacc = 0.0f;
#pragma unroll
        for (int c = 0; c < 4; ++c) {
            const int xi = x0 + (c & 1);
            const int yi = y0 + (c >> 1);
            const float wgt = ((c & 1) ? wx1 : wx0) * ((c >> 1) ? wy1 : wy0);
            if (xi >= 0 && xi < GW_ && yi >= 0 && yi < GH_) {  // wave-uniform branch
                const float2 kv = reinterpret_cast<const float2*>(
                    kvb + (size_t)(yi * GW_ + xi) * 1024)[lane];
                kacc = fmaf(wgt, kv.x, kacc);
                vacc = fmaf(wgt, kv.y, vacc);
            }
        }
        float tsum = qv * kacc;
#pragma unroll
        for (int s = 32; s > 0; s >>= 1) tsum += __shfl_xor(tsum, s, 64);
        lg[p] = tsum * 0.125f;  // HD^-0.5
        sv[p] = vacc;
        mx = fmaxf(mx, lg[p]);
    }

    float ssum = 0.0f, o = 0.0f;
#pragma unroll
    for (int p = 0; p < P_; ++p) {
        const float e = __expf(lg[p] - mx);
        ssum += e;
        o = fmaf(e, sv[p], o);
    }
    o /= ssum;

    a_bf[(tok0 + n) * 512 + hh * 64 + lane] = f2b(o);
}

// ---------------------------------------------------------------------------
extern "C" void kernel_launch(void* const* d_in, const int* in_sizes, int n_in,
                              void* d_out, int out_size, void* d_ws, size_t ws_size,
                              hipStream_t stream) {
    const float* x    = (const float*)d_in[0];
    const float* Wq   = (const float*)d_in[1];
    const float* bq   = (const float*)d_in[2];
    const float* Woff = (const float*)d_in[3];
    const float* boff = (const float*)d_in[4];
    const float* Wkv  = (const float*)d_in[5];
    const float* bkv  = (const float*)d_in[6];
    const float* Wo   = (const float*)d_in[7];
    const float* bo   = (const float*)d_in[8];
    float* out = (float*)d_out;

    // Workspace layout (~65.5 MB total)
    char* ws = (char*)d_ws;
    unsigned short* q_bf   = (unsigned short*)ws;                 ws += (size_t)M_ * 512 * 2;   // 8 MB
    float*          off_ws = (float*)ws;                          ws += (size_t)M_ * 144 * 4;   // 4.7 MB
    float*          kv2    = (float*)ws;                          ws += (size_t)M_ * 1024 * 4;  // 33.5 MB
    unsigned short* a_bf   = (unsigned short*)ws;                 ws += (size_t)M_ * 512 * 2;   // 8 MB
    unsigned short* x_bf   = (unsigned short*)ws;                 ws += (size_t)M_ * 512 * 2;   // 8 MB
    unsigned short* wq_bf  = (unsigned short*)ws;                 ws += (size_t)512 * 512 * 2;
    unsigned short* wkv_bf = (unsigned short*)ws;                 ws += (size_t)1024 * 512 * 2;
    unsigned short* wo_bf  = (unsigned short*)ws;                 ws += (size_t)512 * 512 * 2;

    const dim3 blk(256);

    // 0) cast x, Wq, Wkv, Wo to bf16
    cast_multi<<<dim3(5120), blk, 0, stream>>>(x, Wq, Wkv, Wo, x_bf, wq_bf, wkv_bf, wo_bf);

    // 1) off = tanh(x @ Woff^T + boff) * 4  -- fp32 (precision-critical: pixel coords)
    gemm_bt<true><<<dim3(3, M_ / 64), blk, 0, stream>>>(x, Woff, boff, off_ws, M_, D_, 144);

    // 2) q = x @ Wq^T + bq  (bf16 MFMA, bf16 out)
    gemm_mfma<1><<<dim3(512 / 128, M_ / 128), blk, 0, stream>>>(
        x_bf, wq_bf, bq, q_bf, M_, D_, 512);

    // 3) kv = x @ Wkv^T + bkv  (bf16 MFMA, interleaved fp32 out)
    gemm_mfma<2><<<dim3(1024 / 128, M_ / 128), blk, 0, stream>>>(
        x_bf, wkv_bf, bkv, kv2, M_, D_, 1024);

    // 4) sampling + attention
    attn_sample<<<dim3((B_ * H_ * N_) / 4), blk, 0, stream>>>(q_bf, off_ws, kv2, a_bf);

    // 5) out = attn @ Wo^T + bo  (bf16 MFMA, fp32 out)
    gemm_mfma<0><<<dim3(512 / 128, M_ / 128), blk, 0, stream>>>(
        a_bf, wo_bf, bo, out, M_, D_, 512);
}

// Round 4
// 235.419 us; speedup vs baseline: 2.0207x; 1.2431x over previous
//
#include <hip/hip_runtime.h>
#include <hip/hip_bf16.h>

// Problem constants (fixed by the reference module)
static constexpr int B_  = 2;
static constexpr int N_  = 4096;
static constexpr int D_  = 512;
static constexpr int H_  = 8;
static constexpr int P_  = 9;
static constexpr int GH_ = 16;   // grid h
static constexpr int GW_ = 256;  // grid w
static constexpr int M_  = B_ * N_;  // 8192 tokens

typedef __attribute__((ext_vector_type(8))) short bf16x8;
typedef __attribute__((ext_vector_type(4))) float f32x4;

__device__ __forceinline__ unsigned short f2b(float f) {
    __hip_bfloat16 h = __float2bfloat16(f);  // round-to-nearest
    return *reinterpret_cast<unsigned short*>(&h);
}
__device__ __forceinline__ float b2f(unsigned short u) {
    return __uint_as_float(((unsigned int)u) << 16);
}
__device__ __forceinline__ float b2f_lo(unsigned int u) { return __uint_as_float(u << 16); }
__device__ __forceinline__ float b2f_hi(unsigned int u) { return __uint_as_float(u & 0xffff0000u); }

// ---------------------------------------------------------------------------
// Cast fp32 -> bf16. Ranges (float4 units):
//   x (dual hi/lo) 1048576 | Wq 65536 | Wkv 131072 | Wo 65536 |
//   Woff (dual) 18432 | zero-pad woff rows 144..255: 14336
__global__ __launch_bounds__(256) void cast_multi(
    const float* __restrict__ x,   const float* __restrict__ wq,
    const float* __restrict__ wkv, const float* __restrict__ wo,
    const float* __restrict__ woff,
    unsigned short* __restrict__ x_hi, unsigned short* __restrict__ x_lo,
    unsigned short* __restrict__ wqkv, unsigned short* __restrict__ wob,
    unsigned short* __restrict__ woff_hi, unsigned short* __restrict__ woff_lo) {
    int g = blockIdx.x * 256 + threadIdx.x;

    if (g < 1048576) {  // x -> hi + lo
        float4 v = reinterpret_cast<const float4*>(x)[g];
        ushort4 hi, lo;
        hi.x = f2b(v.x); hi.y = f2b(v.y); hi.z = f2b(v.z); hi.w = f2b(v.w);
        lo.x = f2b(v.x - b2f(hi.x)); lo.y = f2b(v.y - b2f(hi.y));
        lo.z = f2b(v.z - b2f(hi.z)); lo.w = f2b(v.w - b2f(hi.w));
        reinterpret_cast<ushort4*>(x_hi)[g] = hi;
        reinterpret_cast<ushort4*>(x_lo)[g] = lo;
        return;
    }
    g -= 1048576;
    if (g < 65536) {  // Wq -> wqkv rows 0..511
        float4 v = reinterpret_cast<const float4*>(wq)[g];
        ushort4 o; o.x = f2b(v.x); o.y = f2b(v.y); o.z = f2b(v.z); o.w = f2b(v.w);
        reinterpret_cast<ushort4*>(wqkv)[g] = o;
        return;
    }
    g -= 65536;
    if (g < 131072) {  // Wkv -> wqkv rows 512..1535
        float4 v = reinterpret_cast<const float4*>(wkv)[g];
        ushort4 o; o.x = f2b(v.x); o.y = f2b(v.y); o.z = f2b(v.z); o.w = f2b(v.w);
        reinterpret_cast<ushort4*>(wqkv)[65536 + g] = o;
        return;
    }
    g -= 131072;
    if (g < 65536) {  // Wo
        float4 v = reinterpret_cast<const float4*>(wo)[g];
        ushort4 o; o.x = f2b(v.x); o.y = f2b(v.y); o.z = f2b(v.z); o.w = f2b(v.w);
        reinterpret_cast<ushort4*>(wob)[g] = o;
        return;
    }
    g -= 65536;
    if (g < 18432) {  // Woff rows 0..143 -> hi + lo
        float4 v = reinterpret_cast<const float4*>(woff)[g];
        ushort4 hi, lo;
        hi.x = f2b(v.x); hi.y = f2b(v.y); hi.z = f2b(v.z); hi.w = f2b(v.w);
        lo.x = f2b(v.x - b2f(hi.x)); lo.y = f2b(v.y - b2f(hi.y));
        lo.z = f2b(v.z - b2f(hi.z)); lo.w = f2b(v.w - b2f(hi.w));
        reinterpret_cast<ushort4*>(woff_hi)[g] = hi;
        reinterpret_cast<ushort4*>(woff_lo)[g] = lo;
        return;
    }
    g -= 18432;
    // zero-pad rows 144..255 of woff_hi / woff_lo (g in [0, 14336))
    ushort4 z = {0, 0, 0, 0};
    reinterpret_cast<ushort4*>(woff_hi)[18432 + g] = z;
    reinterpret_cast<ushort4*>(woff_lo)[18432 + g] = z;
}

// ---------------------------------------------------------------------------
// Shared MFMA K-loop for one (A, W) segment: 128x128 tile, BK=32,
// global_load_lds width=16 staging, 16x16x32 bf16 MFMA, 4 waves x 4x4 frags.
__device__ __forceinline__ void gemm_seg(const unsigned short* __restrict__ A,
                                         const unsigned short* __restrict__ W,
                                         int m0, int n0, int K,
                                         short* As, short* Bs,
                                         f32x4 (&acc)[4][4], int wave, int lane) {
    const int gi0 = wave * 128 + lane;
    const int gi1 = gi0 + 64;
    const int rA0 = gi0 >> 2, c0 = (gi0 & 3) * 8;
    const int rA1 = gi1 >> 2, c1 = (gi1 & 3) * 8;

    const unsigned short* pa0 = A + (size_t)(m0 + rA0) * K + c0;
    const unsigned short* pa1 = A + (size_t)(m0 + rA1) * K + c1;
    const unsigned short* pw0 = W + (size_t)(n0 + rA0) * K + c0;
    const unsigned short* pw1 = W + (size_t)(n0 + rA1) * K + c1;

    short* ldsA0 = As + wave * 1024;
    short* ldsA1 = As + wave * 1024 + 512;
    short* ldsB0 = Bs + wave * 1024;
    short* ldsB1 = Bs + wave * 1024 + 512;

    const int wm = wave & 1, wn = wave >> 1;
    const int fr = lane & 15;
    const int fk = (lane >> 4) * 8;

    for (int k0 = 0; k0 < K; k0 += 32) {
        __builtin_amdgcn_global_load_lds(
            (const __attribute__((address_space(1))) void*)(pa0 + k0),
            (__attribute__((address_space(3))) void*)ldsA0, 16, 0, 0);
        __builtin_amdgcn_global_load_lds(
            (const __attribute__((address_space(1))) void*)(pa1 + k0),
            (__attribute__((address_space(3))) void*)ldsA1, 16, 0, 0);
        __builtin_amdgcn_global_load_lds(
            (const __attribute__((address_space(1))) void*)(pw0 + k0),
            (__attribute__((address_space(3))) void*)ldsB0, 16, 0, 0);
        __builtin_amdgcn_global_load_lds(
            (const __attribute__((address_space(1))) void*)(pw1 + k0),
            (__attribute__((address_space(3))) void*)ldsB1, 16, 0, 0);
        __syncthreads();

        bf16x8 af[4], bfr[4];
#pragma unroll
        for (int i = 0; i < 4; ++i)
            af[i] = *reinterpret_cast<const bf16x8*>(
                &As[(wm * 64 + i * 16 + fr) * 32 + fk]);
#pragma unroll
        for (int j = 0; j < 4; ++j)
            bfr[j] = *reinterpret_cast<const bf16x8*>(
                &Bs[(wn * 64 + j * 16 + fr) * 32 + fk]);
#pragma unroll
        for (int i = 0; i < 4; ++i)
#pragma unroll
            for (int j = 0; j < 4; ++j)
                acc[i][j] = __builtin_amdgcn_mfma_f32_16x16x32_bf16(
                    af[i], bfr[j], acc[i][j], 0, 0, 0);
        __syncthreads();
    }
}

// MODE 0: plain fp32 store, stride 512 (out GEMM).
// MODE 1: qkv split: n<512 -> bf16 q; n in [512,1024) -> kv2 k slot;
//         n in [1024,1536) -> kv2 v slot (interleaved fp32).
template <int MODE>
__global__ __launch_bounds__(256) void gemm_mfma(const unsigned short* __restrict__ A,
                                                 const unsigned short* __restrict__ W,
                                                 const float* __restrict__ bias0,
                                                 const float* __restrict__ bias1,
                                                 void* __restrict__ out0,
                                                 void* __restrict__ out1,
                                                 int K) {
    __shared__ short As[128 * 32];
    __shared__ short Bs[128 * 32];
    const int t = threadIdx.x;
    const int wave = t >> 6, lane = t & 63;
    const int m0 = blockIdx.y * 128;
    const int n0 = blockIdx.x * 128;

    f32x4 acc[4][4] = {};
    gemm_seg(A, W, m0, n0, K, As, Bs, acc, wave, lane);

    const int wm = wave & 1, wn = wave >> 1;
    const int ecol = lane & 15;
    const int erow = (lane >> 4) * 4;
#pragma unroll
    for (int i = 0; i < 4; ++i) {
#pragma unroll
        for (int j = 0; j < 4; ++j) {
#pragma unroll
            for (int r = 0; r < 4; ++r) {
                const int m = m0 + wm * 64 + i * 16 + erow + r;
                const int n = n0 + wn * 64 + j * 16 + ecol;
                const float v = acc[i][j][r];
                if (MODE == 0) {
                    ((float*)out0)[(size_t)m * 512 + n] = v + bias0[n];
                } else {
                    if (n < 512)
                        ((unsigned short*)out0)[(size_t)m * 512 + n] = f2b(v + bias0[n]);
                    else if (n < 1024)
                        ((float*)out1)[(size_t)m * 1024 + 2 * (n - 512)] = v + bias1[n - 512];
                    else
                        ((float*)out1)[(size_t)m * 1024 + 2 * (n - 1024) + 1] = v + bias1[n - 512];
                }
            }
        }
    }
}

// Offset head: bf16x3 (x_hi@W_hi + x_hi@W_lo + x_lo@W_hi) ~ fp32 precision.
// tanh(v)*4 epilogue, fp32 store, Nout=144 (W buffers padded to 256 zero rows).
__global__ __launch_bounds__(256) void gemm_off3(const unsigned short* __restrict__ Ah,
                                                 const unsigned short* __restrict__ Al,
                                                 const unsigned short* __restrict__ Wh,
                                                 const unsigned short* __restrict__ Wl,
                                                 const float* __restrict__ bias,
                                                 float* __restrict__ Y) {
    __shared__ short As[128 * 32];
    __shared__ short Bs[128 * 32];
    const int t = threadIdx.x;
    const int wave = t >> 6, lane = t & 63;
    const int m0 = blockIdx.y * 128;
    const int n0 = blockIdx.x * 128;

    f32x4 acc[4][4] = {};
    gemm_seg(Ah, Wh, m0, n0, 512, As, Bs, acc, wave, lane);
    gemm_seg(Ah, Wl, m0, n0, 512, As, Bs, acc, wave, lane);
    gemm_seg(Al, Wh, m0, n0, 512, As, Bs, acc, wave, lane);

    const int wm = wave & 1, wn = wave >> 1;
    const int ecol = lane & 15;
    const int erow = (lane >> 4) * 4;
#pragma unroll
    for (int i = 0; i < 4; ++i) {
#pragma unroll
        for (int j = 0; j < 4; ++j) {
            const int n = n0 + wn * 64 + j * 16 + ecol;
            if (n < 144) {
#pragma unroll
                for (int r = 0; r < 4; ++r) {
                    const int m = m0 + wm * 64 + i * 16 + erow + r;
                    Y[(size_t)m * 144 + n] = tanhf(acc[i][j][r] + bias[n]) * 4.0f;
                }
            }
        }
    }
}

// ---------------------------------------------------------------------------
// One wave = 2 consecutive tokens of one (b, head). Half-wave (32 lanes) per
// token; lane j covers channels 2j, 2j+1 via one float4 (k,v interleaved).
// q_bf:  (B*N, 512) bf16
// off_ws:(B*N, 144) fp32   [token][h*18+p*2+c] (already tanh*4)
// kv2:   (B*N, 1024) fp32  [token][2*(h*64+d)+{0:k,1:v}]
// a_bf:  (B*N, 512) bf16 merged-head attention output
__global__ __launch_bounds__(256) void attn_sample(const unsigned short* __restrict__ q_bf,
                                                   const float* __restrict__ off_ws,
                                                   const float* __restrict__ kv2,
                                                   unsigned short* __restrict__ a_bf) {
    const int lane = threadIdx.x & 63;
    const int half = lane >> 5;
    const int j    = lane & 31;
    const int wid  = blockIdx.x * 4 + (threadIdx.x >> 6);  // [0, 32768)
    const int b    = wid >> 14;          // H*N/2 = 16384 pairs per batch
    const int hh   = (wid >> 11) & 7;    // N/2  = 2048 pairs per head
    const int np   = wid & 2047;
    const int n    = np * 2 + half;

    const int px = n & (GW_ - 1);
    const int py = n >> 8;

    const size_t tok = (size_t)b * N_ + n;
    // q channels 2j, 2j+1 (one dword), pre-scaled by HD^-0.5
    const unsigned int qp = *reinterpret_cast<const unsigned int*>(
        q_bf + tok * 512 + hh * 64 + 2 * j);
    const float q0 = b2f_lo(qp) * 0.125f;
    const float q1 = b2f_hi(qp) * 0.125f;

    const float* offp = off_ws + tok * 144 + hh * 18;
    const float* kvb  = kv2 + (size_t)b * N_ * 1024 + hh * 128 + 4 * j;

    float lg[9], s0[9], s1[9];
    float mx = -1e30f;

#pragma unroll
    for (int p = 0; p < P_; ++p) {
        const float2 o2 = *reinterpret_cast<const float2*>(offp + 2 * p);
        const float sx = (float)px + o2.x;
        const float sy = (float)py + o2.y;
        const float x0f = floorf(sx), y0f = floorf(sy);
        const int x0 = (int)x0f, y0 = (int)y0f;
        const float wx1 = sx - x0f, wy1 = sy - y0f;
        const float wx0 = 1.0f - wx1, wy0 = 1.0f - wy1;

        float k0 = 0.f, k1 = 0.f, v0 = 0.f, v1 = 0.f;
#pragma unroll
        for (int c = 0; c < 4; ++c) {
            const int xi = x0 + (c & 1);
            const int yi = y0 + (c >> 1);
            const float wgt = ((c & 1) ? wx1 : wx0) * ((c >> 1) ? wy1 : wy0);
            if (xi >= 0 && xi < GW_ && yi >= 0 && yi < GH_) {  // uniform per half
                const float4 kvv = *reinterpret_cast<const float4*>(
                    kvb + (size_t)((yi << 8) + xi) * 1024);
                k0 = fmaf(wgt, kvv.x, k0);
                v0 = fmaf(wgt, kvv.y, v0);
                k1 = fmaf(wgt, kvv.z, k1);
                v1 = fmaf(wgt, kvv.w, v1);
            }
        }
        float ts = fmaf(q0, k0, q1 * k1);
#pragma unroll
        for (int s = 16; s > 0; s >>= 1) ts += __shfl_xor(ts, s, 64);  // 32-lane half
        lg[p] = ts;
        s0[p] = v0;
        s1[p] = v1;
        mx = fmaxf(mx, lg[p]);
    }

    float ssum = 0.f, o0 = 0.f, o1 = 0.f;
#pragma unroll
    for (int p = 0; p < P_; ++p) {
        const float e = __expf(lg[p] - mx);
        ssum += e;
        o0 = fmaf(e, s0[p], o0);
        o1 = fmaf(e, s1[p], o1);
    }
    const float rs = 1.0f / ssum;
    const unsigned int pack =
        (unsigned int)f2b(o0 * rs) | ((unsigned int)f2b(o1 * rs) << 16);
    *reinterpret_cast<unsigned int*>(a_bf + tok * 512 + hh * 64 + 2 * j) = pack;
}

// ---------------------------------------------------------------------------
extern "C" void kernel_launch(void* const* d_in, const int* in_sizes, int n_in,
                              void* d_out, int out_size, void* d_ws, size_t ws_size,
                              hipStream_t stream) {
    const float* x    = (const float*)d_in[0];
    const float* bq   = (const float*)d_in[2];
    const float* Woff = (const float*)d_in[3];
    const float* boff = (const float*)d_in[4];
    const float* bkv  = (const float*)d_in[6];
    const float* bo   = (const float*)d_in[8];
    float* out = (float*)d_out;

    // Workspace layout (~63 MB)
    char* ws = (char*)d_ws;
    unsigned short* q_bf    = (unsigned short*)ws; ws += (size_t)M_ * 512 * 2;   // 8 MB
    float*          off_ws  = (float*)ws;          ws += (size_t)M_ * 144 * 4;   // 4.7 MB
    float*          kv2     = (float*)ws;          ws += (size_t)M_ * 1024 * 4;  // 33.5 MB
    unsigned short* xlo_abf = (unsigned short*)ws; ws += (size_t)M_ * 512 * 2;   // 8 MB (x_lo, then a_bf)
    unsigned short* x_hi    = (unsigned short*)ws; ws += (size_t)M_ * 512 * 2;   // 8 MB
    unsigned short* wqkv    = (unsigned short*)ws; ws += (size_t)1536 * 512 * 2;
    unsigned short* wob     = (unsigned short*)ws; ws += (size_t)512 * 512 * 2;
    unsigned short* woff_hi = (unsigned short*)ws; ws += (size_t)256 * 512 * 2;
    unsigned short* woff_lo = (unsigned short*)ws; ws += (size_t)256 * 512 * 2;

    const dim3 blk(256);

    // 0) casts (x -> hi/lo, weights -> bf16, zero-pad woff)
    cast_multi<<<dim3(5248), blk, 0, stream>>>(
        x, (const float*)d_in[1], (const float*)d_in[5], (const float*)d_in[7], Woff,
        x_hi, xlo_abf, wqkv, wob, woff_hi, woff_lo);

    // 1) off = tanh(bf16x3 GEMM + boff) * 4  (fp32-accurate pixel offsets)
    gemm_off3<<<dim3(2, M_ / 128), blk, 0, stream>>>(
        x_hi, xlo_abf, woff_hi, woff_lo, boff, off_ws);

    // 2) fused q + kv GEMM (N=1536, 768 blocks)
    gemm_mfma<1><<<dim3(12, M_ / 128), blk, 0, stream>>>(
        x_hi, wqkv, bq, bkv, q_bf, kv2, D_);

    // 3) sampling + attention (2 tokens per wave) -> a_bf (aliases x_lo, now dead)
    attn_sample<<<dim3((B_ * H_ * N_) / 8), blk, 0, stream>>>(
        q_bf, off_ws, kv2, xlo_abf);

    // 4) out = attn @ Wo^T + bo (fp32 out)
    gemm_mfma<0><<<dim3(4, M_ / 128), blk, 0, stream>>>(
        xlo_abf, wob, bo, nullptr, out, nullptr, D_);
}